// Round 4
// baseline (792.407 us; speedup 1.0000x reference)
//
#include <hip/hip_runtime.h>

#define L_SEQ 4096
#define NSTEP 2047
#define ST_W  (-0.000625f)   // -LR * (2/H) = -0.01/16

// ws layout (bytes):
//  [0,      8192)   table  64x32 f32
//  [8192,  24576)   G      64x64 f32
//  [24576, 26624)   Z0     64x8  f32
//  [26624, 26628)   wacc   uint32
//  [28672, 94208)   flags  256 rows x 64 dwords (bit t&31 of word t>>5)

// ---------------------------------------------------------------------------
// Cross-lane reduction helpers (VALU pipe). Layout: i = lane&7, g = lane>>3.
// ---------------------------------------------------------------------------
__device__ __forceinline__ void redi4(float& a, float& b, float& c, float& d) {
    asm volatile(
        "s_nop 1\n\t"
        "v_add_f32_dpp %0, %0, %0 quad_perm:[1,0,3,2] row_mask:0xf bank_mask:0xf bound_ctrl:0\n\t"
        "v_add_f32_dpp %1, %1, %1 quad_perm:[1,0,3,2] row_mask:0xf bank_mask:0xf bound_ctrl:0\n\t"
        "v_add_f32_dpp %2, %2, %2 quad_perm:[1,0,3,2] row_mask:0xf bank_mask:0xf bound_ctrl:0\n\t"
        "v_add_f32_dpp %3, %3, %3 quad_perm:[1,0,3,2] row_mask:0xf bank_mask:0xf bound_ctrl:0\n\t"
        "v_add_f32_dpp %0, %0, %0 quad_perm:[2,3,0,1] row_mask:0xf bank_mask:0xf bound_ctrl:0\n\t"
        "v_add_f32_dpp %1, %1, %1 quad_perm:[2,3,0,1] row_mask:0xf bank_mask:0xf bound_ctrl:0\n\t"
        "v_add_f32_dpp %2, %2, %2 quad_perm:[2,3,0,1] row_mask:0xf bank_mask:0xf bound_ctrl:0\n\t"
        "v_add_f32_dpp %3, %3, %3 quad_perm:[2,3,0,1] row_mask:0xf bank_mask:0xf bound_ctrl:0\n\t"
        "v_add_f32_dpp %0, %0, %0 row_half_mirror row_mask:0xf bank_mask:0xf bound_ctrl:0\n\t"
        "v_add_f32_dpp %1, %1, %1 row_half_mirror row_mask:0xf bank_mask:0xf bound_ctrl:0\n\t"
        "v_add_f32_dpp %2, %2, %2 row_half_mirror row_mask:0xf bank_mask:0xf bound_ctrl:0\n\t"
        "v_add_f32_dpp %3, %3, %3 row_half_mirror row_mask:0xf bank_mask:0xf bound_ctrl:0"
        : "+v"(a), "+v"(b), "+v"(c), "+v"(d));
}

__device__ __forceinline__ float redg1(float x) {
    float t;
    asm volatile(
        "s_nop 1\n\t"
        "v_add_f32_dpp %0, %0, %0 row_ror:8 row_mask:0xf bank_mask:0xf bound_ctrl:0\n\t"
        "s_nop 1\n\t"
        "v_mov_b32 %1, %0\n\t"
        "s_nop 1\n\t"
        "v_permlane16_swap_b32 %1, %0\n\t"
        "s_nop 0\n\t"
        "v_add_f32 %0, %0, %1\n\t"
        "s_nop 1\n\t"
        "v_mov_b32 %1, %0\n\t"
        "s_nop 1\n\t"
        "v_permlane32_swap_b32 %1, %0\n\t"
        "s_nop 0\n\t"
        "v_add_f32 %0, %0, %1"
        : "+v"(x), "=&v"(t));
    return x;
}

// select Z[r] among 8 regs; r is wave-uniform but forced into a VGPR so the
// compiler emits v_cndmask (not an 8-way scalar branch).
__device__ __forceinline__ float sel8d(const float* Z, int r) {
    int rv;
    asm("v_mov_b32 %0, %1" : "=v"(rv) : "s"(r));
    float a0 = (rv & 1) ? Z[1] : Z[0];
    float a1 = (rv & 1) ? Z[3] : Z[2];
    float a2 = (rv & 1) ? Z[5] : Z[4];
    float a3 = (rv & 1) ? Z[7] : Z[6];
    float b0 = (rv & 2) ? a1 : a0;
    float b1_ = (rv & 2) ? a3 : a2;
    return (rv & 4) ? b1_ : b0;
}

// broadcast: lane gets value from lane 8*(tok>>3)+i  (i4 = i<<2 precomputed)
__device__ __forceinline__ float bperm_row(int tok, int i4, float v) {
    int addr = ((tok & 56) << 2) | i4;
    return __int_as_float(__builtin_amdgcn_ds_bpermute(addr, __float_as_int(v)));
}

// ---------------------------------------------------------------------------
// Phase A: table[v] = LN(e_v + MLP(e_v)); G = table·tableᵀ; Z0 = fc1_w·tableᵀ
// ---------------------------------------------------------------------------
__global__ __launch_bounds__(64) void build_kernel(
    const float* __restrict__ embed, const float* __restrict__ ff1_w,
    const float* __restrict__ ff1_b, const float* __restrict__ ff2_w,
    const float* __restrict__ ff2_b, const float* __restrict__ ln_g,
    const float* __restrict__ ln_b, const float* __restrict__ fc1_w,
    float* __restrict__ table, float* __restrict__ G, float* __restrict__ Z0)
{
    __shared__ float tl[64][32];
    const int v = threadIdx.x;
    float h[32], f[32];
#pragma unroll
    for (int j = 0; j < 32; ++j) { h[j] = embed[v * 32 + j]; f[j] = 0.f; }
    for (int k = 0; k < 64; ++k) {
        float z = ff1_b[k];
#pragma unroll
        for (int j = 0; j < 32; ++j) z += h[j] * ff1_w[k * 32 + j];
        z = fmaxf(z, 0.f);
#pragma unroll
        for (int j = 0; j < 32; ++j) f[j] += z * ff2_w[j * 64 + k];
    }
    float x[32], mu = 0.f;
#pragma unroll
    for (int j = 0; j < 32; ++j) { x[j] = h[j] + f[j] + ff2_b[j]; mu += x[j]; }
    mu *= (1.f / 32.f);
    float var = 0.f;
#pragma unroll
    for (int j = 0; j < 32; ++j) { float d = x[j] - mu; var += d * d; }
    var *= (1.f / 32.f);
    const float inv = rsqrtf(var + 1e-5f);
    float tv[32];
#pragma unroll
    for (int j = 0; j < 32; ++j) {
        tv[j] = ln_g[j] * (x[j] - mu) * inv + ln_b[j];
        tl[v][j] = tv[j];
        table[v * 32 + j] = tv[j];
    }
    __syncthreads();
    for (int u = 0; u < 64; ++u) {
        float acc = 0.f;
#pragma unroll
        for (int j = 0; j < 32; ++j) acc += tv[j] * tl[u][j];
        G[v * 64 + u] = acc;
    }
    for (int i = 0; i < 8; ++i) {
        float acc = 0.f;
#pragma unroll
        for (int j = 0; j < 32; ++j) acc += fc1_w[i * 32 + j] * tv[j];
        Z0[v * 8 + i] = acc;
    }
}

// ---------------------------------------------------------------------------
// Phase B1: write gates. Tokens via chunked per-lane loads + readlane —
// NO scalar-mem / global loads in the steady-state loop.
// ---------------------------------------------------------------------------
__global__ __launch_bounds__(64) void flags_kernel(
    const int* __restrict__ seq, const float* __restrict__ Gg,
    unsigned int* __restrict__ flags, unsigned int* __restrict__ wacc)
{
    __shared__ float Gs[4096];
    const int v = threadIdx.x, b = blockIdx.x;
    for (int idx = v; idx < 4096; idx += 64) Gs[idx] = Gg[idx];
    __syncthreads();
    const int2* sp2 = reinterpret_cast<const int2*>(seq + b * L_SEQ);
    const int l31 = v & 31;

    int2 cbA = sp2[l31];            // chunk 0: lane l = (k,v) of step l
    int2 cbB = sp2[32 + l31];       // chunk 1
    int2 cbC = sp2[64 + l31];       // chunk 2

    float S = 0.f, u = 0.f, tf = 0.f;
    unsigned int word = 0, cnt = 0, vw = 0;

    int tok  = __builtin_amdgcn_readlane(cbA.x, 0);
    int tok1 = __builtin_amdgcn_readlane(cbA.x, 1);
    float grow = Gs[tok * 64 + v];

    for (int t = 0; t < NSTEP; ++t) {
        const int ts = t & 31;
        if (ts == 0 && t) {                       // uniform, 1/32 steps
            cbA = cbB; cbB = cbC;
            int c2 = (t >> 5) + 2; if (c2 > 63) c2 = 63;
            cbC = sp2[c2 * 32 + l31];
        }
        const int idx2 = (t + 2) & 31;
        int ka = __builtin_amdgcn_readlane(cbA.x, idx2);
        int kb = __builtin_amdgcn_readlane(cbB.x, idx2);
        int tok2 = (ts >= 30) ? kb : ka;

        float grow1 = Gs[tok1 * 64 + v];          // prefetch t+1
        float A   = __int_as_float(__builtin_amdgcn_readlane(__float_as_int(S), tok));
        float Gtt = __int_as_float(__builtin_amdgcn_readlane(__float_as_int(grow), tok));
        float r = fmaf(tf * tf, Gtt - 16.f, u) - 2.f * tf * A;
        bool wr = (t == 0) || (r > 0.f);
        word |= (wr ? 1u : 0u) << ts;
        if (ts == 31) {
            vw = (v == (t >> 5)) ? word : vw;
            cnt += __popc(word);
            word = 0;
        }
        u += 2.f * A + Gtt;
        S += grow;
        tf += 1.f;
        grow = grow1; tok = tok1; tok1 = tok2;
    }
    vw = (v == 63) ? word : vw;                   // chunk 63 (bits 0..30)
    cnt += __popc(word);
    flags[b * 64 + v] = vw;
    if (v == 0) atomicAdd(wacc, cnt);
}

// ---------------------------------------------------------------------------
// Phase B2: fast-weight scan, Z-cache form. Zero SMEM/global in the loop.
// Lane (i = tid&7, g = tid>>3): Zr[r]=Z[8g+r][i], W2[4g+c][i], b2[4g+c].
// ---------------------------------------------------------------------------
__global__ __launch_bounds__(64) void scan_kernel(
    const int* __restrict__ seq, const float* __restrict__ tableg,
    const float* __restrict__ Gg, const float* __restrict__ Z0g,
    const float* __restrict__ fc1_b, const float* __restrict__ fc2_w,
    const float* __restrict__ fc2_b, const float* __restrict__ out_w,
    const float* __restrict__ out_b, const unsigned int* __restrict__ flags,
    float* __restrict__ out)
{
    __shared__ float Gs[4096];
    __shared__ float tabs[2048];
    __shared__ float ctx_s[32];
    const int b = blockIdx.x, tid = threadIdx.x;
    const int i = tid & 7, g = tid >> 3;
    const int l31 = tid & 31;
    const int i4 = i << 2;
    for (int idx = tid; idx < 4096; idx += 64) Gs[idx] = Gg[idx];
    for (int idx = tid; idx < 2048; idx += 64) tabs[idx] = tableg[idx];
    __syncthreads();
    const float4* tab4 = reinterpret_cast<const float4*>(tabs);

    float Zr[8];
#pragma unroll
    for (int r = 0; r < 8; ++r) Zr[r] = Z0g[(8 * g + r) * 8 + i];
    float b1 = fc1_b[i];
    float W2r0 = fc2_w[(4 * g + 0) * 8 + i];
    float W2r1 = fc2_w[(4 * g + 1) * 8 + i];
    float W2r2 = fc2_w[(4 * g + 2) * 8 + i];
    float W2r3 = fc2_w[(4 * g + 3) * 8 + i];
    float4 b2r = reinterpret_cast<const float4*>(fc2_b)[g];

    const int2* sp2 = reinterpret_cast<const int2*>(seq + b * L_SEQ);
    unsigned int fwv = flags[b * 64 + tid];      // lane l holds flag word l

    int2 cbA = sp2[l31];
    int2 cbB = sp2[32 + l31];
    int2 cbC = sp2[64 + l31];

    // --- prologue (t=0) ---
    int tokk  = __builtin_amdgcn_readlane(cbA.x, 0);
    int tokv  = __builtin_amdgcn_readlane(cbA.y, 0);
    int tokk1 = __builtin_amdgcn_readlane(cbA.x, 1);
    int tokv1 = __builtin_amdgcn_readlane(cbA.y, 1);

    const float4* gr0 = reinterpret_cast<const float4*>(Gs + tokk * 64 + 8 * g);
    float4 Ga = gr0[0], Gb = gr0[1];
    float4 vc = tab4[tokv * 8 + g];
    float y_pre = bperm_row(tokk, i4, sel8d(Zr, tokk & 7));
    float Gx = 0.f, c_prev = 0.f;
    unsigned int fw = (unsigned int)__builtin_amdgcn_readlane((int)fwv, 0);

#pragma unroll 2
    for (int t = 0; t < NSTEP; ++t) {
        const int ts = t & 31;
        if (ts == 0 && t) {                       // uniform, 1/32 steps
            fw = (unsigned int)__builtin_amdgcn_readlane((int)fwv, t >> 5);
            cbA = cbB; cbB = cbC;
            int c2 = (t >> 5) + 2; if (c2 > 63) c2 = 63;
            cbC = sp2[c2 * 32 + l31];
        }
        const float st = ((fw >> ts) & 1u) ? ST_W : 0.0f;

        // tokens for t+2 (pure readlane, no memory)
        const int idx2 = (t + 2) & 31;
        int ka = __builtin_amdgcn_readlane(cbA.x, idx2);
        int va = __builtin_amdgcn_readlane(cbA.y, idx2);
        int kb = __builtin_amdgcn_readlane(cbB.x, idx2);
        int vb = __builtin_amdgcn_readlane(cbB.y, idx2);
        const bool hi2 = (ts >= 30);
        int tokk2 = hi2 ? kb : ka;
        int tokv2 = hi2 ? vb : va;

        // LDS prefetch for t+1
        const float4* grn = reinterpret_cast<const float4*>(Gs + tokk1 * 64 + 8 * g);
        float4 Gan = grn[0], Gbn = grn[1];
        float Gxn = Gs[tokk * 64 + tokk1];        // G[tok_t][tok_{t+1}]
        float4 vcn = tab4[tokv1 * 8 + g];

        // --- critical path ---
        const float z1 = fmaf(c_prev, Gx, y_pre + b1);
        const float a  = fmaxf(z1, 0.f);

        // gather for t+1 from PRE-update Z (corrected next step via Gxn)
        float y_pre_n = bperm_row(tokk1, i4, sel8d(Zr, tokk1 & 7));

        float p0 = W2r0 * a, p1 = W2r1 * a, p2 = W2r2 * a, p3 = W2r3 * a;
        redi4(p0, p1, p2, p3);
        const float dp0 = p0 + (b2r.x - vc.x);    // 16·dpred
        const float dp1 = p1 + (b2r.y - vc.y);
        const float dp2 = p2 + (b2r.z - vc.z);
        const float dp3 = p3 + (b2r.w - vc.w);
        float q = redg1(fmaf(W2r0, dp0, W2r1 * dp1) + fmaf(W2r2, dp2, W2r3 * dp3));
        const float c = (z1 > 0.f) ? st * q : 0.f;   // = -lr·dz1·wr

        // --- updates ---
        const float u0 = st * dp0, u1 = st * dp1, u2 = st * dp2, u3 = st * dp3;
        W2r0 = fmaf(u0, a, W2r0); W2r1 = fmaf(u1, a, W2r1);
        W2r2 = fmaf(u2, a, W2r2); W2r3 = fmaf(u3, a, W2r3);
        b2r.x += u0; b2r.y += u1; b2r.z += u2; b2r.w += u3;
        b1 += c;
        Zr[0] = fmaf(c, Ga.x, Zr[0]); Zr[1] = fmaf(c, Ga.y, Zr[1]);
        Zr[2] = fmaf(c, Ga.z, Zr[2]); Zr[3] = fmaf(c, Ga.w, Zr[3]);
        Zr[4] = fmaf(c, Gb.x, Zr[4]); Zr[5] = fmaf(c, Gb.y, Zr[5]);
        Zr[6] = fmaf(c, Gb.z, Zr[6]); Zr[7] = fmaf(c, Gb.w, Zr[7]);

        // rotate
        y_pre = y_pre_n; Gx = Gxn; c_prev = c;
        Ga = Gan; Gb = Gbn; vc = vcn;
        tokk = tokk1; tokv = tokv1; tokk1 = tokk2; tokv1 = tokv2;
    }

    // --- query/context ---
    const int tq = seq[b * L_SEQ + (L_SEQ - 1)];
    float yq = bperm_row(tq, i4, sel8d(Zr, tq & 7));
    const float zq = yq + b1;
    const float aq = fmaxf(zq, 0.f);
    float c0 = W2r0 * aq, c1 = W2r1 * aq, c2 = W2r2 * aq, c3 = W2r3 * aq;
    redi4(c0, c1, c2, c3);
    if (i == 0) {
        ctx_s[4 * g + 0] = c0 + b2r.x;
        ctx_s[4 * g + 1] = c1 + b2r.y;
        ctx_s[4 * g + 2] = c2 + b2r.z;
        ctx_s[4 * g + 3] = c3 + b2r.w;
    }
    __syncthreads();

    float acc = out_b[tid];
#pragma unroll
    for (int j = 0; j < 32; ++j) acc += ctx_s[j] * out_w[tid * 32 + j];
    out[b * 64 + tid] = acc;
}

__global__ void finalize_kernel(const unsigned int* __restrict__ wacc,
                                float* __restrict__ out)
{
    out[16384] = (float)(*wacc) / 524032.0f;   // B * n = 256 * 2047
}

// ---------------------------------------------------------------------------
extern "C" void kernel_launch(void* const* d_in, const int* in_sizes, int n_in,
                              void* d_out, int out_size, void* d_ws, size_t ws_size,
                              hipStream_t stream)
{
    const int*   seq   = (const int*)  d_in[0];
    const float* embed = (const float*)d_in[1];
    const float* ff1_w = (const float*)d_in[2];
    const float* ff1_b = (const float*)d_in[3];
    const float* ff2_w = (const float*)d_in[4];
    const float* ff2_b = (const float*)d_in[5];
    const float* ln_g  = (const float*)d_in[6];
    const float* ln_b  = (const float*)d_in[7];
    const float* fc1_w = (const float*)d_in[8];
    const float* fc1_b = (const float*)d_in[9];
    const float* fc2_w = (const float*)d_in[10];
    const float* fc2_b = (const float*)d_in[11];
    const float* out_w = (const float*)d_in[12];
    const float* out_b = (const float*)d_in[13];

    float* out = (float*)d_out;
    char* ws = (char*)d_ws;
    float*        table = (float*)(ws + 0);
    float*        G     = (float*)(ws + 8192);
    float*        Z0    = (float*)(ws + 24576);
    unsigned int* wacc  = (unsigned int*)(ws + 26624);
    unsigned int* flags = (unsigned int*)(ws + 28672);

    hipMemsetAsync(wacc, 0, sizeof(unsigned int), stream);
    hipLaunchKernelGGL(build_kernel, dim3(1), dim3(64), 0, stream,
                       embed, ff1_w, ff1_b, ff2_w, ff2_b, ln_g, ln_b, fc1_w,
                       table, G, Z0);
    hipLaunchKernelGGL(flags_kernel, dim3(256), dim3(64), 0, stream,
                       seq, G, flags, wacc);
    hipLaunchKernelGGL(scan_kernel, dim3(256), dim3(64), 0, stream,
                       seq, table, G, Z0, fc1_b, fc2_w, fc2_b,
                       out_w, out_b, flags, out);
    hipLaunchKernelGGL(finalize_kernel, dim3(1), dim3(1), 0, stream, wacc, out);
}

// Round 5
// 625.326 us; speedup vs baseline: 1.2672x; 1.2672x over previous
//
#include <hip/hip_runtime.h>

#define L_SEQ 4096
#define NSTEP 2047
#define ST_W  (-0.000625f)   // -LR * (2/H) = -0.01/16

// ws layout (bytes):
//  [0,      8192)   table  64x32 f32
//  [8192,  24576)   G      64x64 f32
//  [24576, 26624)   Z0     64x8  f32
//  [26624, 26628)   wacc   f32

// ---------------------------------------------------------------------------
// Cross-lane reduction helpers (VALU pipe). Layout: i = lane&7, g = lane>>3.
// ---------------------------------------------------------------------------
__device__ __forceinline__ void redi4(float& a, float& b, float& c, float& d) {
    asm volatile(
        "s_nop 1\n\t"
        "v_add_f32_dpp %0, %0, %0 quad_perm:[1,0,3,2] row_mask:0xf bank_mask:0xf bound_ctrl:0\n\t"
        "v_add_f32_dpp %1, %1, %1 quad_perm:[1,0,3,2] row_mask:0xf bank_mask:0xf bound_ctrl:0\n\t"
        "v_add_f32_dpp %2, %2, %2 quad_perm:[1,0,3,2] row_mask:0xf bank_mask:0xf bound_ctrl:0\n\t"
        "v_add_f32_dpp %3, %3, %3 quad_perm:[1,0,3,2] row_mask:0xf bank_mask:0xf bound_ctrl:0\n\t"
        "v_add_f32_dpp %0, %0, %0 quad_perm:[2,3,0,1] row_mask:0xf bank_mask:0xf bound_ctrl:0\n\t"
        "v_add_f32_dpp %1, %1, %1 quad_perm:[2,3,0,1] row_mask:0xf bank_mask:0xf bound_ctrl:0\n\t"
        "v_add_f32_dpp %2, %2, %2 quad_perm:[2,3,0,1] row_mask:0xf bank_mask:0xf bound_ctrl:0\n\t"
        "v_add_f32_dpp %3, %3, %3 quad_perm:[2,3,0,1] row_mask:0xf bank_mask:0xf bound_ctrl:0\n\t"
        "v_add_f32_dpp %0, %0, %0 row_half_mirror row_mask:0xf bank_mask:0xf bound_ctrl:0\n\t"
        "v_add_f32_dpp %1, %1, %1 row_half_mirror row_mask:0xf bank_mask:0xf bound_ctrl:0\n\t"
        "v_add_f32_dpp %2, %2, %2 row_half_mirror row_mask:0xf bank_mask:0xf bound_ctrl:0\n\t"
        "v_add_f32_dpp %3, %3, %3 row_half_mirror row_mask:0xf bank_mask:0xf bound_ctrl:0"
        : "+v"(a), "+v"(b), "+v"(c), "+v"(d));
}

__device__ __forceinline__ float redg1(float x) {
    float t;
    asm volatile(
        "s_nop 1\n\t"
        "v_add_f32_dpp %0, %0, %0 row_ror:8 row_mask:0xf bank_mask:0xf bound_ctrl:0\n\t"
        "s_nop 1\n\t"
        "v_mov_b32 %1, %0\n\t"
        "s_nop 1\n\t"
        "v_permlane16_swap_b32 %1, %0\n\t"
        "s_nop 0\n\t"
        "v_add_f32 %0, %0, %1\n\t"
        "s_nop 1\n\t"
        "v_mov_b32 %1, %0\n\t"
        "s_nop 1\n\t"
        "v_permlane32_swap_b32 %1, %0\n\t"
        "s_nop 0\n\t"
        "v_add_f32 %0, %0, %1"
        : "+v"(x), "=&v"(t));
    return x;
}

// select Z[r] among 8 regs; r wave-uniform, forced into VGPR -> v_cndmask form
__device__ __forceinline__ float sel8d(const float* Z, int r) {
    int rv;
    asm("v_mov_b32 %0, %1" : "=v"(rv) : "s"(r));
    float a0 = (rv & 1) ? Z[1] : Z[0];
    float a1 = (rv & 1) ? Z[3] : Z[2];
    float a2 = (rv & 1) ? Z[5] : Z[4];
    float a3 = (rv & 1) ? Z[7] : Z[6];
    float b0 = (rv & 2) ? a1 : a0;
    float b1_ = (rv & 2) ? a3 : a2;
    return (rv & 4) ? b1_ : b0;
}

__device__ __forceinline__ float bperm_row(int tok, int i4, float v) {
    int addr = ((tok & 56) << 2) | i4;
    return __int_as_float(__builtin_amdgcn_ds_bpermute(addr, __float_as_int(v)));
}

__device__ __forceinline__ int rli(int x, int l) {
    return __builtin_amdgcn_readlane(x, l);
}
__device__ __forceinline__ float rlf(float x, int l) {
    return __int_as_float(__builtin_amdgcn_readlane(__float_as_int(x), l));
}

// ---------------------------------------------------------------------------
// Phase A: table[v] = LN(e_v + MLP(e_v)); G = table·tableᵀ; Z0 = fc1_w·tableᵀ
// ---------------------------------------------------------------------------
__global__ __launch_bounds__(64) void build_kernel(
    const float* __restrict__ embed, const float* __restrict__ ff1_w,
    const float* __restrict__ ff1_b, const float* __restrict__ ff2_w,
    const float* __restrict__ ff2_b, const float* __restrict__ ln_g,
    const float* __restrict__ ln_b, const float* __restrict__ fc1_w,
    float* __restrict__ table, float* __restrict__ G, float* __restrict__ Z0)
{
    __shared__ float tl[64][32];
    const int v = threadIdx.x;
    float h[32], f[32];
#pragma unroll
    for (int j = 0; j < 32; ++j) { h[j] = embed[v * 32 + j]; f[j] = 0.f; }
    for (int k = 0; k < 64; ++k) {
        float z = ff1_b[k];
#pragma unroll
        for (int j = 0; j < 32; ++j) z += h[j] * ff1_w[k * 32 + j];
        z = fmaxf(z, 0.f);
#pragma unroll
        for (int j = 0; j < 32; ++j) f[j] += z * ff2_w[j * 64 + k];
    }
    float x[32], mu = 0.f;
#pragma unroll
    for (int j = 0; j < 32; ++j) { x[j] = h[j] + f[j] + ff2_b[j]; mu += x[j]; }
    mu *= (1.f / 32.f);
    float var = 0.f;
#pragma unroll
    for (int j = 0; j < 32; ++j) { float d = x[j] - mu; var += d * d; }
    var *= (1.f / 32.f);
    const float inv = rsqrtf(var + 1e-5f);
    float tv[32];
#pragma unroll
    for (int j = 0; j < 32; ++j) {
        tv[j] = ln_g[j] * (x[j] - mu) * inv + ln_b[j];
        tl[v][j] = tv[j];
        table[v * 32 + j] = tv[j];
    }
    __syncthreads();
    for (int u = 0; u < 64; ++u) {
        float acc = 0.f;
#pragma unroll
        for (int j = 0; j < 32; ++j) acc += tv[j] * tl[u][j];
        G[v * 64 + u] = acc;
    }
    for (int i = 0; i < 8; ++i) {
        float acc = 0.f;
#pragma unroll
        for (int j = 0; j < 32; ++j) acc += fc1_w[i * 32 + j] * tv[j];
        Z0[v * 8 + i] = acc;
    }
}

// ---------------------------------------------------------------------------
// Phase B: fused gate + fast-weight scan. One wave per batch row.
// Lane (i=tid&7, g=tid>>3): Zr[r]=Z[8g+r][i], W2[4g+c][i], b2[4g+c].
// Gate side-chain uses lane index v=tid: S[v] = Σ_{s<t} G[tok_s][v].
// All DS ops issued one full step before use; no SMEM/global in the loop.
// ---------------------------------------------------------------------------
__global__ __launch_bounds__(64) void scan_kernel(
    const int* __restrict__ seq, const float* __restrict__ tableg,
    const float* __restrict__ Gg, const float* __restrict__ Z0g,
    const float* __restrict__ fc1_b, const float* __restrict__ fc2_w,
    const float* __restrict__ fc2_b, const float* __restrict__ out_w,
    const float* __restrict__ out_b, float* __restrict__ out,
    float* __restrict__ wacc)
{
    __shared__ float Gs[4096];
    __shared__ float tabs[2048];
    __shared__ float ctx_s[32];
    const int b = blockIdx.x, tid = threadIdx.x;
    const int i = tid & 7, g = tid >> 3;
    const int l31 = tid & 31;
    const int i4 = i << 2;
    for (int idx = tid; idx < 4096; idx += 64) Gs[idx] = Gg[idx];
    for (int idx = tid; idx < 2048; idx += 64) tabs[idx] = tableg[idx];
    __syncthreads();
    const float4* tab4 = reinterpret_cast<const float4*>(tabs);

    // --- model state ---
    float Zr[8];
#pragma unroll
    for (int r = 0; r < 8; ++r) Zr[r] = Z0g[(8 * g + r) * 8 + i];
    float b1 = fc1_b[i];
    float W2r0 = fc2_w[(4 * g + 0) * 8 + i];
    float W2r1 = fc2_w[(4 * g + 1) * 8 + i];
    float W2r2 = fc2_w[(4 * g + 2) * 8 + i];
    float W2r3 = fc2_w[(4 * g + 3) * 8 + i];
    float4 b2r = reinterpret_cast<const float4*>(fc2_b)[g];

    const float dG = Gs[tid * 65];     // G[v][v] in a register

    // --- token chunks (global, 1 load / 32 steps) ---
    const int2* sp2 = reinterpret_cast<const int2*>(seq + b * L_SEQ);
    int2 cbA = sp2[l31];
    int2 cbB = sp2[32 + l31];
    int2 cbC = sp2[64 + l31];

    int k0 = rli(cbA.x, 0), v0 = rli(cbA.y, 0);
    int k1 = rli(cbA.x, 1), v1 = rli(cbA.y, 1);

    // --- t=0 consumption data (only prologue-latency, once) ---
    float Sr_c = Gs[k0 * 64 + tid];
    const float4* gr0 = reinterpret_cast<const float4*>(Gs + k0 * 64 + 8 * g);
    float4 Ga_c = gr0[0], Gb_c = gr0[1];
    float4 vc0 = tab4[v0 * 8 + g];
    float es0 = b2r.x - vc0.x, es1 = b2r.y - vc0.y;
    float es2 = b2r.z - vc0.z, es3 = b2r.w - vc0.w;
    float yb = bperm_row(k0, i4, sel8d(Zr, k0 & 7)) + b1;
    float gB1 = 0.f, c_prev = 0.f;

    // --- gate state ---
    float S = 0.f, u = 0.f, tf = 0.f, nwf = 0.f;

#pragma unroll 2
    for (int t = 0; t < NSTEP; ++t) {
        const int ts = t & 31;
        if (ts == 0 && t) {
            cbA = cbB; cbB = cbC;
            int c2 = (t >> 5) + 2; if (c2 > 63) c2 = 63;
            cbC = sp2[c2 * 32 + l31];
        }
        // tokens for t+2 (no memory)
        const int idx2 = (t + 2) & 31;
        const bool hi2 = (ts >= 30);
        int cx = hi2 ? cbB.x : cbA.x;
        int cy = hi2 ? cbB.y : cbA.y;
        int k2 = rli(cx, idx2);
        int v2 = rli(cy, idx2);

        // --- issue ALL DS for step t+1 now (full step of slack) ---
        float y_n = bperm_row(k1, i4, sel8d(Zr, k1 & 7));  // reads Z_{t-1}
        float Sr_n = Gs[k1 * 64 + tid];
        const float4* grn = reinterpret_cast<const float4*>(Gs + k1 * 64 + 8 * g);
        float4 Ga_n = grn[0], Gb_n = grn[1];
        float4 vc_n = tab4[v1 * 8 + g];
        float gB1n = Gs[k0 * 64 + k1];                     // G[k_t][k_{t+1}]

        // --- gate (side chain; all operands uniform or per-lane local) ---
        const float A   = rlf(S, k0);
        const float Gtt = rlf(dG, k0);
        const float tsq = tf * tf;
        const float r = fmaf(tsq, Gtt - 16.f, u) - (tf + tf) * A;
        const bool wr = (r > 0.f) || (t == 0);
        nwf += wr ? 1.f : 0.f;
        u = fmaf(2.f, A, u) + Gtt;
        S += Sr_c;
        tf += 1.f;
        const float st = wr ? ST_W : 0.f;

        // --- forward critical path ---
        const float z1 = fmaf(c_prev, gB1, yb);
        const float a  = fmaxf(z1, 0.f);
        float p0 = W2r0 * a, p1 = W2r1 * a, p2 = W2r2 * a, p3 = W2r3 * a;
        redi4(p0, p1, p2, p3);
        const float dp0 = p0 + es0, dp1 = p1 + es1;
        const float dp2 = p2 + es2, dp3 = p3 + es3;
        float q = redg1(fmaf(W2r0, dp0, W2r1 * dp1) + fmaf(W2r2, dp2, W2r3 * dp3));
        const float c = (z1 > 0.f) ? st * q : 0.f;    // = -lr·dz1 (0 if no write)

        // --- updates (off critical path) ---
        const float u0 = st * dp0, u1 = st * dp1, u2 = st * dp2, u3 = st * dp3;
        W2r0 = fmaf(u0, a, W2r0); W2r1 = fmaf(u1, a, W2r1);
        W2r2 = fmaf(u2, a, W2r2); W2r3 = fmaf(u3, a, W2r3);
        b2r.x += u0; b2r.y += u1; b2r.z += u2; b2r.w += u3;
        const float yb_n = y_n + b1;   // uses b1_{t-1} (pre-update)
        b1 += c;
        Zr[0] = fmaf(c, Ga_c.x, Zr[0]); Zr[1] = fmaf(c, Ga_c.y, Zr[1]);
        Zr[2] = fmaf(c, Ga_c.z, Zr[2]); Zr[3] = fmaf(c, Ga_c.w, Zr[3]);
        Zr[4] = fmaf(c, Gb_c.x, Zr[4]); Zr[5] = fmaf(c, Gb_c.y, Zr[5]);
        Zr[6] = fmaf(c, Gb_c.z, Zr[6]); Zr[7] = fmaf(c, Gb_c.w, Zr[7]);
        es0 = b2r.x - vc_n.x; es1 = b2r.y - vc_n.y;
        es2 = b2r.z - vc_n.z; es3 = b2r.w - vc_n.w;

        // rotate
        yb = yb_n; gB1 = gB1n + 1.f; c_prev = c;
        Sr_c = Sr_n; Ga_c = Ga_n; Gb_c = Gb_n;
        k0 = k1; k1 = k2; v1 = v2;
    }

    // --- query/context ---
    const int tq = seq[b * L_SEQ + (L_SEQ - 1)];
    float yq = bperm_row(tq, i4, sel8d(Zr, tq & 7));
    const float zq = yq + b1;
    const float aq = fmaxf(zq, 0.f);
    float c0 = W2r0 * aq, c1 = W2r1 * aq, c2 = W2r2 * aq, c3 = W2r3 * aq;
    redi4(c0, c1, c2, c3);
    if (i == 0) {
        ctx_s[4 * g + 0] = c0 + b2r.x;
        ctx_s[4 * g + 1] = c1 + b2r.y;
        ctx_s[4 * g + 2] = c2 + b2r.z;
        ctx_s[4 * g + 3] = c3 + b2r.w;
    }
    __syncthreads();

    float acc = out_b[tid];
#pragma unroll
    for (int j = 0; j < 32; ++j) acc += ctx_s[j] * out_w[tid * 32 + j];
    out[b * 64 + tid] = acc;

    if (tid == 0) atomicAdd(wacc, nwf);   // nwf integer-valued: exact
}

__global__ void finalize_kernel(const float* __restrict__ wacc,
                                float* __restrict__ out)
{
    out[16384] = wacc[0] * (1.0f / 524032.0f);   // / (B * n) = 256 * 2047
}

// ---------------------------------------------------------------------------
extern "C" void kernel_launch(void* const* d_in, const int* in_sizes, int n_in,
                              void* d_out, int out_size, void* d_ws, size_t ws_size,
                              hipStream_t stream)
{
    const int*   seq   = (const int*)  d_in[0];
    const float* embed = (const float*)d_in[1];
    const float* ff1_w = (const float*)d_in[2];
    const float* ff1_b = (const float*)d_in[3];
    const float* ff2_w = (const float*)d_in[4];
    const float* ff2_b = (const float*)d_in[5];
    const float* ln_g  = (const float*)d_in[6];
    const float* ln_b  = (const float*)d_in[7];
    const float* fc1_w = (const float*)d_in[8];
    const float* fc1_b = (const float*)d_in[9];
    const float* fc2_w = (const float*)d_in[10];
    const float* fc2_b = (const float*)d_in[11];
    const float* out_w = (const float*)d_in[12];
    const float* out_b = (const float*)d_in[13];

    float* out = (float*)d_out;
    char* ws = (char*)d_ws;
    float* table = (float*)(ws + 0);
    float* G     = (float*)(ws + 8192);
    float* Z0    = (float*)(ws + 24576);
    float* wacc  = (float*)(ws + 26624);

    hipMemsetAsync(wacc, 0, sizeof(float), stream);
    hipLaunchKernelGGL(build_kernel, dim3(1), dim3(64), 0, stream,
                       embed, ff1_w, ff1_b, ff2_w, ff2_b, ln_g, ln_b, fc1_w,
                       table, G, Z0);
    hipLaunchKernelGGL(scan_kernel, dim3(256), dim3(64), 0, stream,
                       seq, table, G, Z0, fc1_b, fc2_w, fc2_b,
                       out_w, out_b, out, wacc);
    hipLaunchKernelGGL(finalize_kernel, dim3(1), dim3(1), 0, stream, wacc, out);
}